// Round 13
// baseline (749.482 us; speedup 1.0000x reference)
//
#include <hip/hip_runtime.h>

#define HH 2048
#define WW 2048
#define HWTOT 4194304
#define BIGL 4194304
#define CSZ 227
#define NCLS 4
#define MINSZ 64
#define TF 1.1920928955078125e-7f
#define EPSB 5e-3f
#define LISTCAP 4000000

// d_out layout (bytes). d_out = 64MiB = 4 regions x 16MiB.
#define OFF_LABA 0u
#define OFF_LABB (1u<<24)
#define OFF_H1C  ((1u<<24) + 3538944u)
#define OFF_H2C  ((1u<<24) + 7077888u)
#define OFF_CAND ((1u<<24) + 9437184u)
#define OFF_CAND16 ((1u<<24) + 9437184u + 524288u)
#define OFF_COUNTS (2u<<24)
#define OFF_W2R  ((3u<<24) + 4096u)
#define OFF_W1P  ((3u<<24) + 65536u)
#define OFF_LIST ((3u<<24) + 131072u)

typedef __attribute__((ext_vector_type(8))) short bf16x8;
typedef __attribute__((ext_vector_type(4))) float f32x4;
typedef __attribute__((ext_vector_type(2))) float f32x2;
typedef unsigned int uint;
typedef unsigned short ushort;
typedef unsigned long long u64;

struct Meta {
  int lids[16];
  int valid[16];
  int cls[16];
  int bby0[16], bby1[16], bbx0[16], bbx1[16];
};

struct CCShared {
  int edgeL[24][100];
  int edgeR[24][100];
  int4 vtop[8][25];
  int4 vbot[8][25];
};  // 25600 bytes <= 32768

__device__ __forceinline__ ushort f2bf(float f) {
  uint u = __float_as_uint(f);
  u += 0x7fffu + ((u >> 16) & 1u);
  return (ushort)(u >> 16);
}
__device__ __forceinline__ float bf2f(ushort h) {
  return __uint_as_float(((uint)h) << 16);
}

// hbuf swizzled index: px stride 32 shorts; g XOR'd with (px&3)^((px>>2)&3)
#define HSWZ(px, g) ((px) * 32 + ((((g) ^ ((px) & 3) ^ (((px) >> 2) & 3))) << 3))

// ---------------- prep: w2 -> bf16 hi/lo A-frag; w1 -> paired w1p; zero ws ------
__global__ __launch_bounds__(256) void prep_kernel(const float* __restrict__ w2,
                                                   const float* __restrict__ w1,
                                                   ushort* __restrict__ wfrag,
                                                   float* __restrict__ w1p,
                                                   int* __restrict__ ws) {
  if (blockIdx.x == 0 && threadIdx.x < 32) ws[threadIdx.x] = 0;
  int i = blockIdx.x * 256 + threadIdx.x;
  // w1p[(g*9+t)*8 + r] = w1[(g*8+r)*9 + t]  (288 entries)
  if (i < 288) {
    int g = i / 72, rem = i - g * 72;
    int t = rem >> 3, r = rem & 7;
    w1p[i] = w1[(g * 8 + r) * 9 + t];
  }
  if (i >= 18432) return;
  int fid = i >> 9, within = i & 511;
  int lane = within >> 3, j = within & 7;
  int tap = fid >> 2, m = (fid >> 1) & 1, p = fid & 1;
  int row = lane & 15, kgrp = lane >> 4;
  int ci = kgrp * 8 + j, oc = m * 16 + row;
  float w = w2[oc * 288 + ci * 9 + tap];
  ushort hb = f2bf(w);
  ushort val = hb;
  if (p) { float lof = w - bf2f(hb); val = f2bf(lof); }
  wfrag[i] = val;
}

// ---------------- fused cascade: 32x16 tile, 512 threads (frozen) --------------
__global__ __launch_bounds__(512) void cascade_kernel(
    const float* __restrict__ x, const float* __restrict__ w1p,
    const ushort* __restrict__ wfrag, const float* __restrict__ w3,
    int* __restrict__ lab, int* __restrict__ list, int* __restrict__ list_count) {
  __shared__ float xs[20][36];
  __shared__ __align__(16) short hbuf[2][19584];  // [hi/lo][HSWZ(px,g)], px<612

  const int tid = threadIdx.x;
  const int ox = blockIdx.x * 32, oy = blockIdx.y * 16;

  for (int i = tid; i < 720; i += 512) {
    int r = i / 36, c = i - r * 36;
    int gy = oy - 2 + r, gx = ox - 2 + c;
    float v = 0.f;
    if ((unsigned)gy < (unsigned)HH && (unsigned)gx < (unsigned)WW) v = x[gy * WW + gx];
    xs[r][c] = v;
  }
  __syncthreads();

  for (int px = tid; px < 612; px += 512) {
    const int hr = px / 34, hc = px - hr * 34;
    const int gy = oy - 1 + hr, gx = ox - 1 + hc;
    const bool inimg = ((unsigned)gy < (unsigned)HH) && ((unsigned)gx < (unsigned)WW);
    float a9[9];
#pragma unroll
    for (int du = 0; du < 3; ++du)
#pragma unroll
      for (int dv = 0; dv < 3; ++dv) a9[du * 3 + dv] = xs[hr + du][hc + dv];
#pragma unroll 1
    for (int g = 0; g < 4; ++g) {
      f32x2 sv2[4];
#pragma unroll
      for (int q = 0; q < 4; ++q) sv2[q] = (f32x2){0.f, 0.f};
#pragma unroll
      for (int t = 0; t < 9; ++t) {
        f32x2 a2 = {a9[t], a9[t]};
        const f32x2* wp = (const f32x2*)&w1p[(g * 9 + t) * 8];
#pragma unroll
        for (int q = 0; q < 4; ++q) {
#if __has_builtin(__builtin_elementwise_fma)
          sv2[q] = __builtin_elementwise_fma(a2, wp[q], sv2[q]);
#else
          sv2[q].x = fmaf(a9[t], wp[q].x, sv2[q].x);
          sv2[q].y = fmaf(a9[t], wp[q].y, sv2[q].y);
#endif
        }
      }
      uint hp[4], lp[4];
#pragma unroll
      for (int q = 0; q < 4; ++q) {
        float s0 = inimg ? fmaxf(sv2[q].x, 0.f) : 0.f;
        float s1 = inimg ? fmaxf(sv2[q].y, 0.f) : 0.f;
        uint h2u;
        asm("v_cvt_pk_bf16_f32 %0, %1, %2" : "=v"(h2u) : "v"(s0), "v"(s1));
        float h0 = __uint_as_float(h2u << 16);
        float h1 = __uint_as_float(h2u & 0xffff0000u);
        uint l2u;
        asm("v_cvt_pk_bf16_f32 %0, %1, %2" : "=v"(l2u) : "v"(s0 - h0), "v"(s1 - h1));
        hp[q] = h2u; lp[q] = l2u;
      }
      *(int4*)&hbuf[0][HSWZ(px, g)] = make_int4(hp[0], hp[1], hp[2], hp[3]);
      *(int4*)&hbuf[1][HSWZ(px, g)] = make_int4(lp[0], lp[1], lp[2], lp[3]);
    }
  }
  __syncthreads();

  const int wv = tid >> 6, lane = tid & 63;
  const int col = lane & 15, kg = lane >> 4;
  const f32x4 zero4 = {0.f, 0.f, 0.f, 0.f};
  f32x4 acc[4][2];
#pragma unroll
  for (int i = 0; i < 4; ++i) { acc[i][0] = zero4; acc[i][1] = zero4; }

  const int4* wf4 = (const int4*)wfrag;
#pragma unroll 3
  for (int tap = 0; tap < 9; ++tap) {
    const int ty = tap / 3, tx = tap - ty * 3;
    bf16x8 a[2][2];
#pragma unroll
    for (int m = 0; m < 2; ++m)
#pragma unroll
      for (int p = 0; p < 2; ++p)
        a[m][p] = __builtin_bit_cast(bf16x8, wf4[(tap * 4 + m * 2 + p) * 64 + lane]);
#pragma unroll
    for (int ni = 0; ni < 4; ++ni) {
      const int nt = wv * 4 + ni;
      const int px = ((nt >> 1) + ty) * 34 + (nt & 1) * 16 + tx + col;
      bf16x8 bh = __builtin_bit_cast(bf16x8, *(const int4*)&hbuf[0][HSWZ(px, kg)]);
      bf16x8 bl = __builtin_bit_cast(bf16x8, *(const int4*)&hbuf[1][HSWZ(px, kg)]);
      acc[ni][0] = __builtin_amdgcn_mfma_f32_16x16x32_bf16(a[0][0], bh, acc[ni][0], 0, 0, 0);
      acc[ni][1] = __builtin_amdgcn_mfma_f32_16x16x32_bf16(a[1][0], bh, acc[ni][1], 0, 0, 0);
      acc[ni][0] = __builtin_amdgcn_mfma_f32_16x16x32_bf16(a[0][1], bh, acc[ni][0], 0, 0, 0);
      acc[ni][1] = __builtin_amdgcn_mfma_f32_16x16x32_bf16(a[1][1], bh, acc[ni][1], 0, 0, 0);
      acc[ni][0] = __builtin_amdgcn_mfma_f32_16x16x32_bf16(a[0][0], bl, acc[ni][0], 0, 0, 0);
      acc[ni][1] = __builtin_amdgcn_mfma_f32_16x16x32_bf16(a[1][0], bl, acc[ni][1], 0, 0, 0);
    }
  }

#pragma unroll 1
  for (int ni = 0; ni < 4; ++ni) {
    const int nt = wv * 4 + ni;
    float z = 0.f;
#pragma unroll
    for (int m = 0; m < 2; ++m)
#pragma unroll
      for (int r = 0; r < 4; ++r)
        z = fmaf(w3[m * 16 + kg * 4 + r], fmaxf(acc[ni][m][r], 0.f), z);
    z += __shfl_xor(z, 16);
    z += __shfl_xor(z, 32);
    const int gy = oy + (nt >> 1), gx = ox + (nt & 1) * 16 + col;
    const int p = gy * WW + gx;
    const bool act = lane < 16;
    if (act) lab[p] = (z > TF) ? p : BIGL;
    bool need = act && (fabsf(z - TF) < EPSB);
    unsigned long long mms = __ballot(need);
    if (mms) {
      int cnt = __popcll(mms);
      int prefix = __popcll(mms & ((1ull << lane) - 1ull));
      int basei = 0;
      if (need && prefix == 0) basei = atomicAdd(list_count, cnt);
      int srcl = __ffsll((long long)mms) - 1;
      basei = __shfl(basei, srcl);
      if (need && basei + prefix < LISTCAP) list[basei + prefix] = p;
    }
  }
}

// ---------------- f64 recheck of band pixels (2 threads per px, ci-split) ------
__global__ __launch_bounds__(256) void recheck_kernel(
    const float* __restrict__ x, const float* __restrict__ w1,
    const float* __restrict__ w2, const float* __restrict__ w3,
    const int* __restrict__ list, const int* __restrict__ list_count,
    int* __restrict__ lab) {
  int n = *list_count;
  if (n > LISTCAP) n = LISTCAP;
  const int half = threadIdx.x & 1;
  for (int i = (blockIdx.x * 256 + threadIdx.x) >> 1; i < n; i += (2048 * 256) >> 1) {
    int p = list[i];
    int py = p >> 11, px = p & 2047;
    float xv[5][5];
#pragma unroll
    for (int u = 0; u < 5; ++u)
#pragma unroll
      for (int v = 0; v < 5; ++v) {
        int gy = py - 2 + u, gx = px - 2 + v;
        xv[u][v] = ((unsigned)gy < (unsigned)HH && (unsigned)gx < (unsigned)WW)
                       ? x[gy * WW + gx] : 0.f;
      }
    double acc2[32];
#pragma unroll
    for (int j = 0; j < 32; ++j) acc2[j] = 0.0;
    const int ci0 = half * 16;
#pragma unroll 1
    for (int ci = ci0; ci < ci0 + 16; ++ci) {
      float h1v[3][3];
#pragma unroll
      for (int u = 0; u < 3; ++u)
#pragma unroll
        for (int v = 0; v < 3; ++v) {
          int gy = py - 1 + u, gx = px - 1 + v;
          float s = 0.f;
#pragma unroll
          for (int t9 = 0; t9 < 9; ++t9)
            s = fmaf(xv[u + t9 / 3][v + t9 % 3], w1[ci * 9 + t9], s);
          bool inb = ((unsigned)gy < (unsigned)HH) && ((unsigned)gx < (unsigned)WW);
          h1v[u][v] = (inb && (s > 0.f)) ? s : 0.f;
        }
#pragma unroll
      for (int dy = 0; dy < 3; ++dy)
#pragma unroll
        for (int dx = 0; dx < 3; ++dx) {
          double hd = (double)h1v[dy][dx];
#pragma unroll
          for (int j = 0; j < 32; ++j)
            acc2[j] = fma(hd, (double)w2[j * 288 + ci * 9 + dy * 3 + dx], acc2[j]);
        }
    }
    double zz = 0.0;
#pragma unroll
    for (int j = 0; j < 32; ++j) {
      double other = __shfl_xor(acc2[j], 1);
      double tot = (half == 0) ? (acc2[j] + other) : (other + acc2[j]);
      zz = fma((double)w3[j], tot > 0.0 ? tot : 0.0, zz);
    }
    if (half == 0) lab[p] = (zz > 1.1920928955078125e-7) ? p : BIGL;
  }
}

__device__ __forceinline__ void hist_add(int* hkey, int* hval, int label, int run) {
  unsigned hh = (((unsigned)label * 2654435761u) >> 20) & 4095u;
  for (;;) {
    int k = atomicCAS(&hkey[hh], -1, label);
    if (k == -1 || k == label) { atomicAdd(&hval[hh], run); break; }
    hh = (hh + 1) & 4095u;
  }
}

// ---------------- CC: 16 exact steps + early-exit; optional fused histogram ----
__global__ __launch_bounds__(256) void cc16_kernel(const int* __restrict__ in,
                                                   int* __restrict__ out,
                                                   int* __restrict__ counts,
                                                   int dohist) {
  __shared__ __align__(16) char smem[32768];
  CCShared* S = (CCShared*)smem;
  __shared__ int chg[2];
  const int tid = threadIdx.x;
  const int bx = blockIdx.x & 31, by = blockIdx.x >> 5;
  const int ox0 = bx * 64 - 16, oy0 = by * 64 - 16;
  const bool act = tid < 192;
  const int g = tid % 24, s = tid / 24;
  const int gx = ox0 + g * 4;
  const bool colin = ((unsigned)gx < (unsigned)WW);
  int4 c[12];
#pragma unroll
  for (int r = 0; r < 12; ++r) c[r] = make_int4(BIGL, BIGL, BIGL, BIGL);
  if (act && colin) {
#pragma unroll
    for (int r = 0; r < 12; ++r) {
      int gy = oy0 + s * 12 + r;
      if ((unsigned)gy < (unsigned)HH) c[r] = *(const int4*)(in + gy * WW + gx);
    }
  }
  if (tid < 2) chg[tid] = 1;
  __syncthreads();  // also covers chg init

#pragma unroll 1
  for (int step = 0; step < 16; ++step) {
    const int cur = step & 1, nxt = cur ^ 1;
    if (act) {
      *(int4*)&S->edgeL[g][s * 12 + 0] = make_int4(c[0].x, c[1].x, c[2].x, c[3].x);
      *(int4*)&S->edgeL[g][s * 12 + 4] = make_int4(c[4].x, c[5].x, c[6].x, c[7].x);
      *(int4*)&S->edgeL[g][s * 12 + 8] = make_int4(c[8].x, c[9].x, c[10].x, c[11].x);
      *(int4*)&S->edgeR[g][s * 12 + 0] = make_int4(c[0].w, c[1].w, c[2].w, c[3].w);
      *(int4*)&S->edgeR[g][s * 12 + 4] = make_int4(c[4].w, c[5].w, c[6].w, c[7].w);
      *(int4*)&S->edgeR[g][s * 12 + 8] = make_int4(c[8].w, c[9].w, c[10].w, c[11].w);
      S->vtop[s][g] = c[0];
      S->vbot[s][g] = c[11];
    }
    if (tid == 0) chg[nxt] = 0;  // pre-barrier reset; set-stores happen post-barrier
    __syncthreads();
    if (chg[cur] == 0) break;  // previous step reached fixed point -> rest identity
    if (act) {
      int lf[12], rt[12];
      if (g > 0) {
        int4 a0 = *(const int4*)&S->edgeR[g - 1][s * 12 + 0];
        int4 a1 = *(const int4*)&S->edgeR[g - 1][s * 12 + 4];
        int4 a2 = *(const int4*)&S->edgeR[g - 1][s * 12 + 8];
        lf[0] = a0.x; lf[1] = a0.y; lf[2] = a0.z; lf[3] = a0.w;
        lf[4] = a1.x; lf[5] = a1.y; lf[6] = a1.z; lf[7] = a1.w;
        lf[8] = a2.x; lf[9] = a2.y; lf[10] = a2.z; lf[11] = a2.w;
      } else {
#pragma unroll
        for (int r = 0; r < 12; ++r) lf[r] = BIGL;
      }
      if (g < 23) {
        int4 a0 = *(const int4*)&S->edgeL[g + 1][s * 12 + 0];
        int4 a1 = *(const int4*)&S->edgeL[g + 1][s * 12 + 4];
        int4 a2 = *(const int4*)&S->edgeL[g + 1][s * 12 + 8];
        rt[0] = a0.x; rt[1] = a0.y; rt[2] = a0.z; rt[3] = a0.w;
        rt[4] = a1.x; rt[5] = a1.y; rt[6] = a1.z; rt[7] = a1.w;
        rt[8] = a2.x; rt[9] = a2.y; rt[10] = a2.z; rt[11] = a2.w;
      } else {
#pragma unroll
        for (int r = 0; r < 12; ++r) rt[r] = BIGL;
      }
      int4 prev = (s > 0) ? S->vbot[s - 1][g] : make_int4(BIGL, BIGL, BIGL, BIGL);
      int4 dnlast = (s < 7) ? S->vtop[s + 1][g] : make_int4(BIGL, BIGL, BIGL, BIGL);
      int diff = 0;
#pragma unroll
      for (int r = 0; r < 12; ++r) {
        int4 cc2 = c[r];
        int4 d = (r < 11) ? c[r + 1] : dnlast;
        int4 nr;
        nr.x = (cc2.x == BIGL) ? BIGL : min(min(cc2.x, cc2.y), min(min(prev.x, d.x), lf[r]));
        nr.y = (cc2.y == BIGL) ? BIGL : min(min(cc2.y, min(cc2.x, cc2.z)), min(prev.y, d.y));
        nr.z = (cc2.z == BIGL) ? BIGL : min(min(cc2.z, min(cc2.y, cc2.w)), min(prev.z, d.z));
        nr.w = (cc2.w == BIGL) ? BIGL : min(min(cc2.w, min(cc2.z, rt[r])), min(prev.w, d.w));
        diff |= (nr.x != cc2.x) | (nr.y != cc2.y) | (nr.z != cc2.z) | (nr.w != cc2.w);
        c[r] = nr;
        prev = cc2;
      }
      if (diff) chg[nxt] = 1;
    }
    __syncthreads();
  }

  if (dohist) {
    // edge buffers dead; alias as 4096-slot hash (16KB keys + 16KB vals)
    int* hkey = (int*)smem;
    int* hval = (int*)(smem + 16384);
    __syncthreads();
    for (int i = tid; i < 4096; i += 256) { hkey[i] = -1; hval[i] = 0; }
    __syncthreads();
    if (act && g >= 4 && g < 20) {
      int prevl = -1, run = 0;
#pragma unroll 1
      for (int r = 0; r < 12; ++r) {
        int row = s * 12 + r;
        if (row < 16 || row >= 80) continue;
        int v[4] = {c[r].x, c[r].y, c[r].z, c[r].w};
#pragma unroll
        for (int j = 0; j < 4; ++j) {
          int l = v[j];
          if (l == prevl) { run++; continue; }
          if (prevl >= 0 && prevl != BIGL) hist_add(hkey, hval, prevl, run);
          prevl = l; run = 1;
        }
      }
      if (prevl >= 0 && prevl != BIGL) hist_add(hkey, hval, prevl, run);
    }
    __syncthreads();
    for (int i = tid; i < 4096; i += 256)
      if (hkey[i] >= 0) atomicAdd(&counts[hkey[i]], hval[i]);
  }

  // store central 64x64: g in [4,20), rows s*12+r in [16,80)
  if (act && g >= 4 && g < 20) {
#pragma unroll
    for (int r = 0; r < 12; ++r) {
      int row = s * 12 + r;
      if (row >= 16 && row < 80) {
        int gy = oy0 + row;
        *(int4*)(out + gy * WW + gx) = c[r];
      }
    }
  }
}

// ---------------- collect labels with count >= MINSZ (wave-aggregated) --------
__global__ __launch_bounds__(256) void cand_kernel(const int* __restrict__ counts,
                                                   int2* __restrict__ cand,
                                                   int* __restrict__ cand_count) {
  int i = blockIdx.x * 256 + threadIdx.x;
  int lane = threadIdx.x & 63;
  int c = (i < HWTOT) ? counts[i] : 0;
  bool hit = (c >= MINSZ);
  unsigned long long m = __ballot(hit);
  if (m) {
    int cnt = __popcll(m);
    int prefix = __popcll(m & ((1ull << lane) - 1ull));
    int base = 0;
    if (hit && prefix == 0) base = atomicAdd(cand_count, cnt);
    int srcl = __ffsll((long long)m) - 1;
    base = __shfl(base, srcl);
    if (hit && base + prefix < 65536) cand[base + prefix] = make_int2(c, i);
  }
}

// ---------------- top-16 stage 1: 32 blocks x local top-16 (keys unique) ------
__global__ __launch_bounds__(256) void top16a_kernel(const int2* __restrict__ cand,
                                                     const int* __restrict__ cand_count,
                                                     u64* __restrict__ cand16) {
  __shared__ u64 skey[256];
  int tid = threadIdx.x;
  int n = *cand_count;
  if (n > 65536) n = 65536;
  u64 prev = ~0ull;
  for (int r = 0; r < 16; ++r) {
    u64 best = 0ull;
    for (int i = blockIdx.x * 256 + tid; i < n; i += 32 * 256) {
      int2 cc = cand[i];
      u64 key = ((u64)(unsigned)cc.x << 32) | (unsigned)(BIGL - cc.y);
      if (key < prev && key > best) best = key;
    }
    skey[tid] = best;
    __syncthreads();
    for (int st = 128; st > 0; st >>= 1) {
      if (tid < st && skey[tid + st] > skey[tid]) skey[tid] = skey[tid + st];
      __syncthreads();
    }
    u64 blockbest = skey[0];
    if (tid == 0) cand16[blockIdx.x * 16 + r] = blockbest;
    prev = blockbest;
    __syncthreads();
  }
}

// ---------------- top-16 stage 2: 512 keys -> global top-16; init meta --------
__global__ __launch_bounds__(256) void top16b_kernel(const u64* __restrict__ cand16,
                                                     Meta* __restrict__ meta) {
  __shared__ u64 skey[256];
  int tid = threadIdx.x;
  u64 k0 = cand16[tid], k1 = cand16[tid + 256];
  u64 prev = ~0ull;
  for (int r = 0; r < 16; ++r) {
    u64 best = 0ull;
    if (k0 < prev && k0 > best) best = k0;
    if (k1 < prev && k1 > best) best = k1;
    skey[tid] = best;
    __syncthreads();
    for (int st = 128; st > 0; st >>= 1) {
      if (tid < st && skey[tid + st] > skey[tid]) skey[tid] = skey[tid + st];
      __syncthreads();
    }
    u64 blockbest = skey[0];
    if (tid == 0) {
      if (blockbest > 0ull) {
        meta->lids[r] = BIGL - (int)(blockbest & 0xffffffffull);
        meta->valid[r] = 1;
      } else {
        meta->lids[r] = -1;
        meta->valid[r] = 0;
      }
    }
    prev = blockbest;
    __syncthreads();
  }
  if (tid < 16) {
    meta->bby0[tid] = HH; meta->bby1[tid] = -1;
    meta->bbx0[tid] = WW; meta->bbx1[tid] = -1;
    meta->cls[tid] = 0;
  }
}

// ---------------- bounding boxes of selected labels ----------------
__global__ __launch_bounds__(256) void bbox_kernel(const int* __restrict__ lab,
                                                   Meta* __restrict__ meta) {
  __shared__ int lid_s[16];
  __shared__ int by0[16], by1[16], bx0[16], bx1[16];
  int tid = threadIdx.x;
  if (tid < 16) {
    lid_s[tid] = meta->lids[tid];
    by0[tid] = HH; by1[tid] = -1; bx0[tid] = WW; bx1[tid] = -1;
  }
  __syncthreads();
  int t = blockIdx.x * 256 + tid;
  int p = t * 8;
  int y = p >> 11, xbase = p & 2047;
  int4 a = *(const int4*)(lab + p), b = *(const int4*)(lab + p + 4);
  int v[8] = {a.x, a.y, a.z, a.w, b.x, b.y, b.z, b.w};
  int prev = BIGL, kprev = -1, xs = 0, xe = 0;
#pragma unroll
  for (int j = 0; j < 8; ++j) {
    int l = v[j];
    if (l == prev) { xe = xbase + j; continue; }
    if (kprev >= 0) {
      atomicMin(&by0[kprev], y); atomicMax(&by1[kprev], y);
      atomicMin(&bx0[kprev], xs); atomicMax(&bx1[kprev], xe);
    }
    prev = l; xs = xe = xbase + j; kprev = -1;
    if (l != BIGL) {
      for (int k = 0; k < 16; ++k)
        if (lid_s[k] == l) { kprev = k; break; }
    }
  }
  if (kprev >= 0) {
    atomicMin(&by0[kprev], y); atomicMax(&by1[kprev], y);
    atomicMin(&bx0[kprev], xs); atomicMax(&bx1[kprev], xe);
  }
  __syncthreads();
  if (tid < 16 && by1[tid] >= 0) {
    atomicMin(&meta->bby0[tid], by0[tid]); atomicMax(&meta->bby1[tid], by1[tid]);
    atomicMin(&meta->bbx0[tid], bx0[tid]); atomicMax(&meta->bbx1[tid], bx1[tid]);
  }
}

// ---------------- classifier conv1 with fused ROI bilinear (7-row LDS staging) --
__global__ __launch_bounds__(256) void cconv1_kernel(const float* __restrict__ img,
                                                     const float* __restrict__ cw1,
                                                     const Meta* __restrict__ meta,
                                                     float* __restrict__ h1c) {
  int k = blockIdx.y, oy = blockIdx.x;
  if (!meta->valid[k]) return;
  __shared__ float srow[7][CSZ];
  float y0 = (float)meta->bby0[k], y1 = (float)meta->bby1[k];
  float x0 = (float)meta->bbx0[k], x1 = (float)meta->bbx1[k];
  for (int idx = threadIdx.x; idx < 7 * CSZ; idx += 256) {
    int rr = idx / CSZ, j = idx - rr * CSZ;
    int i = oy * 4 + rr;
    float ti = (float)i / 226.f, tj = (float)j / 226.f;
    float gy = y0 + ti * (y1 - y0);
    float gx = x0 + tj * (x1 - x0);
    int yf = (int)floorf(gy); yf = yf < 0 ? 0 : (yf > HH - 2 ? HH - 2 : yf);
    int xf = (int)floorf(gx); xf = xf < 0 ? 0 : (xf > WW - 2 ? WW - 2 : xf);
    float fy = gy - (float)yf, fx = gx - (float)xf;
    const float* r0 = img + yf * WW + xf;
    float v00 = r0[0], v01 = r0[1], v10 = r0[WW], v11 = r0[WW + 1];
    srow[rr][j] = (1.f - fy) * ((1.f - fx) * v00 + fx * v01) +
                  fy * ((1.f - fx) * v10 + fx * v11);
  }
  __syncthreads();
  for (int idx = threadIdx.x; idx < 16 * 56; idx += 256) {
    int ch = idx / 56, ox = idx - ch * 56;
    const float* wp = cw1 + ch * 49;
    float s = 0.f;
#pragma unroll
    for (int dy = 0; dy < 7; ++dy)
#pragma unroll
      for (int dx = 0; dx < 7; ++dx)
        s += srow[dy][ox * 4 + dx] * wp[dy * 7 + dx];
    h1c[((k * 16 + ch) * 56 + oy) * 56 + ox] = s > 0.f ? s : 0.f;
  }
}

// ---------------- classifier conv2: 16->32, 3x3, stride 2, VALID ----------------
__global__ __launch_bounds__(256) void cconv2_kernel(const float* __restrict__ h1c,
                                                     const float* __restrict__ cw2,
                                                     const Meta* __restrict__ meta,
                                                     float* __restrict__ h2c) {
  int k = blockIdx.y, oy = blockIdx.x;
  if (!meta->valid[k]) return;
  for (int idx = threadIdx.x; idx < 32 * 27; idx += 256) {
    int ch = idx / 27, ox = idx - ch * 27;
    float s = 0.f;
    for (int ci = 0; ci < 16; ++ci) {
      const float* hp = h1c + ((k * 16 + ci) * 56 + oy * 2) * 56 + ox * 2;
      const float* wp = cw2 + (ch * 16 + ci) * 9;
#pragma unroll
      for (int dy = 0; dy < 3; ++dy)
#pragma unroll
        for (int dx = 0; dx < 3; ++dx) s += hp[dy * 56 + dx] * wp[dy * 3 + dx];
    }
    h2c[((k * 32 + ch) * 27 + oy) * 27 + ox] = s > 0.f ? s : 0.f;
  }
}

// ---------------- global mean pool + fc + argmax ----------------
__global__ __launch_bounds__(256) void poolfc_kernel(const float* __restrict__ h2c,
                                                     const float* __restrict__ fc,
                                                     Meta* __restrict__ meta) {
  int k = blockIdx.x;
  if (!meta->valid[k]) return;
  __shared__ float sums[8][32];
  int tid = threadIdx.x;
  int c = tid & 31, part = tid >> 5;
  float s = 0.f;
  const float* hp = h2c + (k * 32 + c) * 729;
  for (int j = part; j < 729; j += 8) s += hp[j];
  sums[part][c] = s;
  __syncthreads();
  if (tid < 32) {
    float g = 0.f;
#pragma unroll
    for (int p2 = 0; p2 < 8; ++p2) g += sums[p2][tid];
    sums[0][tid] = g / 729.f;
  }
  __syncthreads();
  if (tid == 0) {
    float best = -1e30f;
    int bi = 0;
    for (int j = 0; j < NCLS; ++j) {
      float lg = 0.f;
      for (int c2 = 0; c2 < 32; ++c2) lg += sums[0][c2] * fc[c2 * NCLS + j];
      if (lg > best) { best = lg; bi = j; }
    }
    meta->cls[k] = bi;
  }
}

// ---------------- final: write 4-channel one-hot masks ----------------
__global__ __launch_bounds__(256) void final_kernel(const float* labf,
                                                    const Meta* __restrict__ meta,
                                                    float* out) {
  __shared__ int lid_s[16];
  __shared__ int cls_s[16];
  int tid = threadIdx.x;
  if (tid < 16) {
    lid_s[tid] = meta->valid[tid] ? meta->lids[tid] : -1;
    cls_s[tid] = meta->cls[tid];
  }
  __syncthreads();
  int t = blockIdx.x * 256 + tid;
  int p = t * 4;
  float4 lf = *(const float4*)(labf + p);
  int l4[4] = {__float_as_int(lf.x), __float_as_int(lf.y), __float_as_int(lf.z),
               __float_as_int(lf.w)};
  int cj[4];
#pragma unroll
  for (int j = 0; j < 4; ++j) {
    cj[j] = -1;
    int l = l4[j];
    if (l != BIGL) {
      for (int k = 0; k < 16; ++k)
        if (lid_s[k] == l) { cj[j] = cls_s[k]; break; }
    }
  }
#pragma unroll
  for (int c = 0; c < 4; ++c) {
    float4 w4 = make_float4(cj[0] == c ? 1.f : 0.f, cj[1] == c ? 1.f : 0.f,
                            cj[2] == c ? 1.f : 0.f, cj[3] == c ? 1.f : 0.f);
    *(float4*)(out + (size_t)c * HWTOT + p) = w4;
  }
}

extern "C" void kernel_launch(void* const* d_in, const int* in_sizes, int n_in,
                              void* d_out, int out_size, void* d_ws, size_t ws_size,
                              hipStream_t stream) {
  const float* x = (const float*)d_in[0];
  const float* w1 = (const float*)d_in[1];
  const float* w2 = (const float*)d_in[2];
  const float* w3 = (const float*)d_in[3];
  const float* cw1 = (const float*)d_in[4];
  const float* cw2 = (const float*)d_in[5];
  const float* fc = (const float*)d_in[6];

  char* base = (char*)d_out;
  int* lab_a = (int*)(base + OFF_LABA);
  int* lab_b = (int*)(base + OFF_LABB);
  float* h1c = (float*)(base + OFF_H1C);
  float* h2c = (float*)(base + OFF_H2C);
  int2* cand = (int2*)(base + OFF_CAND);
  u64* cand16 = (u64*)(base + OFF_CAND16);
  int* counts = (int*)(base + OFF_COUNTS);
  ushort* wfrag = (ushort*)(base + OFF_W2R);
  float* w1p = (float*)(base + OFF_W1P);
  int* list = (int*)(base + OFF_LIST);
  int* cand_count = (int*)d_ws;
  int* list_count = (int*)((char*)d_ws + 64);
  Meta* meta = (Meta*)((char*)d_ws + 256);

  hipMemsetAsync(counts, 0, (size_t)(HWTOT + 1) * sizeof(int), stream);

  prep_kernel<<<72, 256, 0, stream>>>(w2, w1, wfrag, w1p, (int*)d_ws);
  cascade_kernel<<<dim3(64, 128), 512, 0, stream>>>(x, w1p, wfrag, w3, lab_a, list,
                                                    list_count);
  recheck_kernel<<<2048, 256, 0, stream>>>(x, w1, w2, w3, list, list_count, lab_a);

  // 64 exact CC steps = 4 launches x 16 steps (early-exit on local fixed point).
  // Last launch also builds the label histogram from the register tile.
  cc16_kernel<<<1024, 256, 0, stream>>>(lab_a, lab_b, counts, 0);
  cc16_kernel<<<1024, 256, 0, stream>>>(lab_b, lab_a, counts, 0);
  cc16_kernel<<<1024, 256, 0, stream>>>(lab_a, lab_b, counts, 0);
  cc16_kernel<<<1024, 256, 0, stream>>>(lab_b, lab_a, counts, 1);
  // final labels in lab_a

  cand_kernel<<<16384, 256, 0, stream>>>(counts, cand, cand_count);
  top16a_kernel<<<32, 256, 0, stream>>>(cand, cand_count, cand16);
  top16b_kernel<<<1, 256, 0, stream>>>(cand16, meta);
  bbox_kernel<<<2048, 256, 0, stream>>>(lab_a, meta);
  cconv1_kernel<<<dim3(56, 16), 256, 0, stream>>>(x, cw1, meta, h1c);
  cconv2_kernel<<<dim3(27, 16), 256, 0, stream>>>(h1c, cw2, meta, h2c);
  poolfc_kernel<<<16, 256, 0, stream>>>(h2c, fc, meta);
  final_kernel<<<4096, 256, 0, stream>>>((const float*)d_out, meta, (float*)d_out);
}

// Round 14
// 660.421 us; speedup vs baseline: 1.1349x; 1.1349x over previous
//
#include <hip/hip_runtime.h>

#define HH 2048
#define WW 2048
#define HWTOT 4194304
#define BIGL 4194304
#define CSZ 227
#define NCLS 4
#define MINSZ 64
#define TF 1.1920928955078125e-7f
#define EPSB 5e-3f
#define LISTCAP 4000000

// d_out layout (bytes). d_out = 64MiB = 4 regions x 16MiB.
#define OFF_LABA 0u
#define OFF_LABB (1u<<24)
#define OFF_H1C  ((1u<<24) + 3538944u)
#define OFF_H2C  ((1u<<24) + 7077888u)
#define OFF_CAND ((1u<<24) + 9437184u)
#define OFF_CAND16 ((1u<<24) + 9437184u + 524288u)
#define OFF_COUNTS (2u<<24)
#define OFF_W2R  ((3u<<24) + 4096u)
#define OFF_W1P  ((3u<<24) + 65536u)
#define OFF_LIST ((3u<<24) + 131072u)

typedef __attribute__((ext_vector_type(8))) short bf16x8;
typedef __attribute__((ext_vector_type(4))) float f32x4;
typedef __attribute__((ext_vector_type(2))) float f32x2;
typedef unsigned int uint;
typedef unsigned short ushort;
typedef unsigned long long u64;

struct Meta {
  int lids[16];
  int valid[16];
  int cls[16];
  int bby0[16], bby1[16], bbx0[16], bbx1[16];
};

__device__ __forceinline__ ushort f2bf(float f) {
  uint u = __float_as_uint(f);
  u += 0x7fffu + ((u >> 16) & 1u);
  return (ushort)(u >> 16);
}
__device__ __forceinline__ float bf2f(ushort h) {
  return __uint_as_float(((uint)h) << 16);
}

// hbuf swizzled index: px stride 32 shorts; g XOR'd with (px&3)^((px>>2)&3)
#define HSWZ(px, g) ((px) * 32 + ((((g) ^ ((px) & 3) ^ (((px) >> 2) & 3))) << 3))

// ---------------- prep: w2 -> bf16 hi/lo A-frag; w1 -> paired w1p; zero ws ------
__global__ __launch_bounds__(256) void prep_kernel(const float* __restrict__ w2,
                                                   const float* __restrict__ w1,
                                                   ushort* __restrict__ wfrag,
                                                   float* __restrict__ w1p,
                                                   int* __restrict__ ws) {
  if (blockIdx.x == 0 && threadIdx.x < 32) ws[threadIdx.x] = 0;
  int i = blockIdx.x * 256 + threadIdx.x;
  // w1p[(g*9+t)*8 + r] = w1[(g*8+r)*9 + t]  (288 entries)
  if (i < 288) {
    int g = i / 72, rem = i - g * 72;
    int t = rem >> 3, r = rem & 7;
    w1p[i] = w1[(g * 8 + r) * 9 + t];
  }
  if (i >= 18432) return;
  int fid = i >> 9, within = i & 511;
  int lane = within >> 3, j = within & 7;
  int tap = fid >> 2, m = (fid >> 1) & 1, p = fid & 1;
  int row = lane & 15, kgrp = lane >> 4;
  int ci = kgrp * 8 + j, oc = m * 16 + row;
  float w = w2[oc * 288 + ci * 9 + tap];
  ushort hb = f2bf(w);
  ushort val = hb;
  if (p) { float lof = w - bf2f(hb); val = f2bf(lof); }
  wfrag[i] = val;
}

// ---------------- fused cascade: 32x16 tile, 512 threads (frozen) --------------
__global__ __launch_bounds__(512) void cascade_kernel(
    const float* __restrict__ x, const float* __restrict__ w1p,
    const ushort* __restrict__ wfrag, const float* __restrict__ w3,
    int* __restrict__ lab, int* __restrict__ list, int* __restrict__ list_count) {
  __shared__ float xs[20][36];
  __shared__ __align__(16) short hbuf[2][19584];  // [hi/lo][HSWZ(px,g)], px<612

  const int tid = threadIdx.x;
  const int ox = blockIdx.x * 32, oy = blockIdx.y * 16;

  for (int i = tid; i < 720; i += 512) {
    int r = i / 36, c = i - r * 36;
    int gy = oy - 2 + r, gx = ox - 2 + c;
    float v = 0.f;
    if ((unsigned)gy < (unsigned)HH && (unsigned)gx < (unsigned)WW) v = x[gy * WW + gx];
    xs[r][c] = v;
  }
  __syncthreads();

  for (int px = tid; px < 612; px += 512) {
    const int hr = px / 34, hc = px - hr * 34;
    const int gy = oy - 1 + hr, gx = ox - 1 + hc;
    const bool inimg = ((unsigned)gy < (unsigned)HH) && ((unsigned)gx < (unsigned)WW);
    float a9[9];
#pragma unroll
    for (int du = 0; du < 3; ++du)
#pragma unroll
      for (int dv = 0; dv < 3; ++dv) a9[du * 3 + dv] = xs[hr + du][hc + dv];
#pragma unroll 1
    for (int g = 0; g < 4; ++g) {
      f32x2 sv2[4];
#pragma unroll
      for (int q = 0; q < 4; ++q) sv2[q] = (f32x2){0.f, 0.f};
#pragma unroll
      for (int t = 0; t < 9; ++t) {
        f32x2 a2 = {a9[t], a9[t]};
        const f32x2* wp = (const f32x2*)&w1p[(g * 9 + t) * 8];
#pragma unroll
        for (int q = 0; q < 4; ++q) {
#if __has_builtin(__builtin_elementwise_fma)
          sv2[q] = __builtin_elementwise_fma(a2, wp[q], sv2[q]);
#else
          sv2[q].x = fmaf(a9[t], wp[q].x, sv2[q].x);
          sv2[q].y = fmaf(a9[t], wp[q].y, sv2[q].y);
#endif
        }
      }
      uint hp[4], lp[4];
#pragma unroll
      for (int q = 0; q < 4; ++q) {
        float s0 = inimg ? fmaxf(sv2[q].x, 0.f) : 0.f;
        float s1 = inimg ? fmaxf(sv2[q].y, 0.f) : 0.f;
        uint h2u;
        asm("v_cvt_pk_bf16_f32 %0, %1, %2" : "=v"(h2u) : "v"(s0), "v"(s1));
        float h0 = __uint_as_float(h2u << 16);
        float h1 = __uint_as_float(h2u & 0xffff0000u);
        uint l2u;
        asm("v_cvt_pk_bf16_f32 %0, %1, %2" : "=v"(l2u) : "v"(s0 - h0), "v"(s1 - h1));
        hp[q] = h2u; lp[q] = l2u;
      }
      *(int4*)&hbuf[0][HSWZ(px, g)] = make_int4(hp[0], hp[1], hp[2], hp[3]);
      *(int4*)&hbuf[1][HSWZ(px, g)] = make_int4(lp[0], lp[1], lp[2], lp[3]);
    }
  }
  __syncthreads();

  const int wv = tid >> 6, lane = tid & 63;
  const int col = lane & 15, kg = lane >> 4;
  const f32x4 zero4 = {0.f, 0.f, 0.f, 0.f};
  f32x4 acc[4][2];
#pragma unroll
  for (int i = 0; i < 4; ++i) { acc[i][0] = zero4; acc[i][1] = zero4; }

  const int4* wf4 = (const int4*)wfrag;
#pragma unroll 3
  for (int tap = 0; tap < 9; ++tap) {
    const int ty = tap / 3, tx = tap - ty * 3;
    bf16x8 a[2][2];
#pragma unroll
    for (int m = 0; m < 2; ++m)
#pragma unroll
      for (int p = 0; p < 2; ++p)
        a[m][p] = __builtin_bit_cast(bf16x8, wf4[(tap * 4 + m * 2 + p) * 64 + lane]);
#pragma unroll
    for (int ni = 0; ni < 4; ++ni) {
      const int nt = wv * 4 + ni;
      const int px = ((nt >> 1) + ty) * 34 + (nt & 1) * 16 + tx + col;
      bf16x8 bh = __builtin_bit_cast(bf16x8, *(const int4*)&hbuf[0][HSWZ(px, kg)]);
      bf16x8 bl = __builtin_bit_cast(bf16x8, *(const int4*)&hbuf[1][HSWZ(px, kg)]);
      acc[ni][0] = __builtin_amdgcn_mfma_f32_16x16x32_bf16(a[0][0], bh, acc[ni][0], 0, 0, 0);
      acc[ni][1] = __builtin_amdgcn_mfma_f32_16x16x32_bf16(a[1][0], bh, acc[ni][1], 0, 0, 0);
      acc[ni][0] = __builtin_amdgcn_mfma_f32_16x16x32_bf16(a[0][1], bh, acc[ni][0], 0, 0, 0);
      acc[ni][1] = __builtin_amdgcn_mfma_f32_16x16x32_bf16(a[1][1], bh, acc[ni][1], 0, 0, 0);
      acc[ni][0] = __builtin_amdgcn_mfma_f32_16x16x32_bf16(a[0][0], bl, acc[ni][0], 0, 0, 0);
      acc[ni][1] = __builtin_amdgcn_mfma_f32_16x16x32_bf16(a[1][0], bl, acc[ni][1], 0, 0, 0);
    }
  }

#pragma unroll 1
  for (int ni = 0; ni < 4; ++ni) {
    const int nt = wv * 4 + ni;
    float z = 0.f;
#pragma unroll
    for (int m = 0; m < 2; ++m)
#pragma unroll
      for (int r = 0; r < 4; ++r)
        z = fmaf(w3[m * 16 + kg * 4 + r], fmaxf(acc[ni][m][r], 0.f), z);
    z += __shfl_xor(z, 16);
    z += __shfl_xor(z, 32);
    const int gy = oy + (nt >> 1), gx = ox + (nt & 1) * 16 + col;
    const int p = gy * WW + gx;
    const bool act = lane < 16;
    if (act) lab[p] = (z > TF) ? p : BIGL;
    bool need = act && (fabsf(z - TF) < EPSB);
    unsigned long long mms = __ballot(need);
    if (mms) {
      int cnt = __popcll(mms);
      int prefix = __popcll(mms & ((1ull << lane) - 1ull));
      int basei = 0;
      if (need && prefix == 0) basei = atomicAdd(list_count, cnt);
      int srcl = __ffsll((long long)mms) - 1;
      basei = __shfl(basei, srcl);
      if (need && basei + prefix < LISTCAP) list[basei + prefix] = p;
    }
  }
}

// ---------------- f64 recheck of band pixels (2 threads per px, ci-split) ------
__global__ __launch_bounds__(256) void recheck_kernel(
    const float* __restrict__ x, const float* __restrict__ w1,
    const float* __restrict__ w2, const float* __restrict__ w3,
    const int* __restrict__ list, const int* __restrict__ list_count,
    int* __restrict__ lab) {
  int n = *list_count;
  if (n > LISTCAP) n = LISTCAP;
  const int half = threadIdx.x & 1;
  for (int i = (blockIdx.x * 256 + threadIdx.x) >> 1; i < n; i += (2048 * 256) >> 1) {
    int p = list[i];
    int py = p >> 11, px = p & 2047;
    float xv[5][5];
#pragma unroll
    for (int u = 0; u < 5; ++u)
#pragma unroll
      for (int v = 0; v < 5; ++v) {
        int gy = py - 2 + u, gx = px - 2 + v;
        xv[u][v] = ((unsigned)gy < (unsigned)HH && (unsigned)gx < (unsigned)WW)
                       ? x[gy * WW + gx] : 0.f;
      }
    double acc2[32];
#pragma unroll
    for (int j = 0; j < 32; ++j) acc2[j] = 0.0;
    const int ci0 = half * 16;
#pragma unroll 1
    for (int ci = ci0; ci < ci0 + 16; ++ci) {
      float h1v[3][3];
#pragma unroll
      for (int u = 0; u < 3; ++u)
#pragma unroll
        for (int v = 0; v < 3; ++v) {
          int gy = py - 1 + u, gx = px - 1 + v;
          float s = 0.f;
#pragma unroll
          for (int t9 = 0; t9 < 9; ++t9)
            s = fmaf(xv[u + t9 / 3][v + t9 % 3], w1[ci * 9 + t9], s);
          bool inb = ((unsigned)gy < (unsigned)HH) && ((unsigned)gx < (unsigned)WW);
          h1v[u][v] = (inb && (s > 0.f)) ? s : 0.f;
        }
#pragma unroll
      for (int dy = 0; dy < 3; ++dy)
#pragma unroll
        for (int dx = 0; dx < 3; ++dx) {
          double hd = (double)h1v[dy][dx];
#pragma unroll
          for (int j = 0; j < 32; ++j)
            acc2[j] = fma(hd, (double)w2[j * 288 + ci * 9 + dy * 3 + dx], acc2[j]);
        }
    }
    // pair reduce: z = sum_j w3[j]*relu(acc_half0[j] + acc_half1[j]) on half==0
    double zz = 0.0;
#pragma unroll
    for (int j = 0; j < 32; ++j) {
      double other = __shfl_xor(acc2[j], 1);
      double tot = (half == 0) ? (acc2[j] + other) : (other + acc2[j]);
      zz = fma((double)w3[j], tot > 0.0 ? tot : 0.0, zz);
    }
    if (half == 0) lab[p] = (zz > 1.1920928955078125e-7) ? p : BIGL;
  }
}

// ---------------- CC: 16 exact steps, 12-row strips in registers, halo 16 ------
__global__ __launch_bounds__(256) void cc16_kernel(const int* __restrict__ in,
                                                   int* __restrict__ out) {
  __shared__ __align__(16) int edgeL[24][100];
  __shared__ __align__(16) int edgeR[24][100];
  __shared__ __align__(16) int4 vtop[8][25];
  __shared__ __align__(16) int4 vbot[8][25];
  const int tid = threadIdx.x;
  const int bx = blockIdx.x & 31, by = blockIdx.x >> 5;
  const int ox0 = bx * 64 - 16, oy0 = by * 64 - 16;
  const bool act = tid < 192;
  const int g = tid % 24, s = tid / 24;
  const int gx = ox0 + g * 4;
  const bool colin = ((unsigned)gx < (unsigned)WW);
  int4 c[12];
#pragma unroll
  for (int r = 0; r < 12; ++r) c[r] = make_int4(BIGL, BIGL, BIGL, BIGL);
  if (act && colin) {
#pragma unroll
    for (int r = 0; r < 12; ++r) {
      int gy = oy0 + s * 12 + r;
      if ((unsigned)gy < (unsigned)HH) c[r] = *(const int4*)(in + gy * WW + gx);
    }
  }
#pragma unroll 1
  for (int step = 0; step < 16; ++step) {
    if (act) {
      *(int4*)&edgeL[g][s * 12 + 0] = make_int4(c[0].x, c[1].x, c[2].x, c[3].x);
      *(int4*)&edgeL[g][s * 12 + 4] = make_int4(c[4].x, c[5].x, c[6].x, c[7].x);
      *(int4*)&edgeL[g][s * 12 + 8] = make_int4(c[8].x, c[9].x, c[10].x, c[11].x);
      *(int4*)&edgeR[g][s * 12 + 0] = make_int4(c[0].w, c[1].w, c[2].w, c[3].w);
      *(int4*)&edgeR[g][s * 12 + 4] = make_int4(c[4].w, c[5].w, c[6].w, c[7].w);
      *(int4*)&edgeR[g][s * 12 + 8] = make_int4(c[8].w, c[9].w, c[10].w, c[11].w);
      vtop[s][g] = c[0];
      vbot[s][g] = c[11];
    }
    __syncthreads();
    if (act) {
      int lf[12], rt[12];
      if (g > 0) {
        int4 a0 = *(const int4*)&edgeR[g - 1][s * 12 + 0];
        int4 a1 = *(const int4*)&edgeR[g - 1][s * 12 + 4];
        int4 a2 = *(const int4*)&edgeR[g - 1][s * 12 + 8];
        lf[0] = a0.x; lf[1] = a0.y; lf[2] = a0.z; lf[3] = a0.w;
        lf[4] = a1.x; lf[5] = a1.y; lf[6] = a1.z; lf[7] = a1.w;
        lf[8] = a2.x; lf[9] = a2.y; lf[10] = a2.z; lf[11] = a2.w;
      } else {
#pragma unroll
        for (int r = 0; r < 12; ++r) lf[r] = BIGL;
      }
      if (g < 23) {
        int4 a0 = *(const int4*)&edgeL[g + 1][s * 12 + 0];
        int4 a1 = *(const int4*)&edgeL[g + 1][s * 12 + 4];
        int4 a2 = *(const int4*)&edgeL[g + 1][s * 12 + 8];
        rt[0] = a0.x; rt[1] = a0.y; rt[2] = a0.z; rt[3] = a0.w;
        rt[4] = a1.x; rt[5] = a1.y; rt[6] = a1.z; rt[7] = a1.w;
        rt[8] = a2.x; rt[9] = a2.y; rt[10] = a2.z; rt[11] = a2.w;
      } else {
#pragma unroll
        for (int r = 0; r < 12; ++r) rt[r] = BIGL;
      }
      int4 prev = (s > 0) ? vbot[s - 1][g] : make_int4(BIGL, BIGL, BIGL, BIGL);
      int4 dnlast = (s < 7) ? vtop[s + 1][g] : make_int4(BIGL, BIGL, BIGL, BIGL);
#pragma unroll
      for (int r = 0; r < 12; ++r) {
        int4 cur = c[r];
        int4 d = (r < 11) ? c[r + 1] : dnlast;
        int4 nr;
        nr.x = (cur.x == BIGL) ? BIGL : min(min(cur.x, cur.y), min(min(prev.x, d.x), lf[r]));
        nr.y = (cur.y == BIGL) ? BIGL : min(min(cur.y, min(cur.x, cur.z)), min(prev.y, d.y));
        nr.z = (cur.z == BIGL) ? BIGL : min(min(cur.z, min(cur.y, cur.w)), min(prev.z, d.z));
        nr.w = (cur.w == BIGL) ? BIGL : min(min(cur.w, min(cur.z, rt[r])), min(prev.w, d.w));
        c[r] = nr;
        prev = cur;
      }
    }
    __syncthreads();
  }
  // store central 64x64: g in [4,20), rows s*12+r in [16,80)
  if (act && g >= 4 && g < 20) {
#pragma unroll
    for (int r = 0; r < 12; ++r) {
      int row = s * 12 + r;
      if (row >= 16 && row < 80) {
        int gy = oy0 + row;
        *(int4*)(out + gy * WW + gx) = c[r];
      }
    }
  }
}

// ---------------- histogram: per-block LDS hash (4096 slots) ----------------
__global__ __launch_bounds__(256) void hist_kernel(const int* __restrict__ lab,
                                                   int* __restrict__ counts) {
  __shared__ int hkey[4096];
  __shared__ int hval[4096];
  int tid = threadIdx.x;
  for (int i = tid; i < 4096; i += 256) { hkey[i] = -1; hval[i] = 0; }
  __syncthreads();
  int t = blockIdx.x * 256 + tid;
  int p = t * 8;
  int4 a = *(const int4*)(lab + p), b = *(const int4*)(lab + p + 4);
  int v[8] = {a.x, a.y, a.z, a.w, b.x, b.y, b.z, b.w};
  int prev = -1, run = 0;
#pragma unroll
  for (int j = 0; j < 8; ++j) {
    int l = v[j];
    if (l == prev) { run++; continue; }
    if (prev >= 0 && prev != BIGL) {
      unsigned hh = (((unsigned)prev * 2654435761u) >> 20) & 4095u;
      for (;;) {
        int k = atomicCAS(&hkey[hh], -1, prev);
        if (k == -1 || k == prev) { atomicAdd(&hval[hh], run); break; }
        hh = (hh + 1) & 4095u;
      }
    }
    prev = l; run = 1;
  }
  if (prev >= 0 && prev != BIGL) {
    unsigned hh = (((unsigned)prev * 2654435761u) >> 20) & 4095u;
    for (;;) {
      int k = atomicCAS(&hkey[hh], -1, prev);
      if (k == -1 || k == prev) { atomicAdd(&hval[hh], run); break; }
      hh = (hh + 1) & 4095u;
    }
  }
  __syncthreads();
  for (int i = tid; i < 4096; i += 256)
    if (hkey[i] >= 0) atomicAdd(&counts[hkey[i]], hval[i]);
}

// ---------------- collect labels with count >= MINSZ (wave-aggregated) --------
__global__ __launch_bounds__(256) void cand_kernel(const int* __restrict__ counts,
                                                   int2* __restrict__ cand,
                                                   int* __restrict__ cand_count) {
  int i = blockIdx.x * 256 + threadIdx.x;
  int lane = threadIdx.x & 63;
  int c = (i < HWTOT) ? counts[i] : 0;
  bool hit = (c >= MINSZ);
  unsigned long long m = __ballot(hit);
  if (m) {
    int cnt = __popcll(m);
    int prefix = __popcll(m & ((1ull << lane) - 1ull));
    int base = 0;
    if (hit && prefix == 0) base = atomicAdd(cand_count, cnt);
    int srcl = __ffsll((long long)m) - 1;
    base = __shfl(base, srcl);
    if (hit && base + prefix < 65536) cand[base + prefix] = make_int2(c, i);
  }
}

// ---------------- top-16 stage 1: 32 blocks x local top-16 (keys unique) ------
__global__ __launch_bounds__(256) void top16a_kernel(const int2* __restrict__ cand,
                                                     const int* __restrict__ cand_count,
                                                     u64* __restrict__ cand16) {
  __shared__ u64 skey[256];
  int tid = threadIdx.x;
  int n = *cand_count;
  if (n > 65536) n = 65536;
  u64 prev = ~0ull;
  for (int r = 0; r < 16; ++r) {
    u64 best = 0ull;
    for (int i = blockIdx.x * 256 + tid; i < n; i += 32 * 256) {
      int2 cc = cand[i];
      u64 key = ((u64)(unsigned)cc.x << 32) | (unsigned)(BIGL - cc.y);
      if (key < prev && key > best) best = key;
    }
    skey[tid] = best;
    __syncthreads();
    for (int st = 128; st > 0; st >>= 1) {
      if (tid < st && skey[tid + st] > skey[tid]) skey[tid] = skey[tid + st];
      __syncthreads();
    }
    u64 blockbest = skey[0];
    if (tid == 0) cand16[blockIdx.x * 16 + r] = blockbest;
    prev = blockbest;
    __syncthreads();
  }
}

// ---------------- top-16 stage 2: 512 keys -> global top-16; init meta --------
__global__ __launch_bounds__(256) void top16b_kernel(const u64* __restrict__ cand16,
                                                     Meta* __restrict__ meta) {
  __shared__ u64 skey[256];
  int tid = threadIdx.x;
  u64 k0 = cand16[tid], k1 = cand16[tid + 256];
  u64 prev = ~0ull;
  for (int r = 0; r < 16; ++r) {
    u64 best = 0ull;
    if (k0 < prev && k0 > best) best = k0;
    if (k1 < prev && k1 > best) best = k1;
    skey[tid] = best;
    __syncthreads();
    for (int st = 128; st > 0; st >>= 1) {
      if (tid < st && skey[tid + st] > skey[tid]) skey[tid] = skey[tid + st];
      __syncthreads();
    }
    u64 blockbest = skey[0];
    if (tid == 0) {
      if (blockbest > 0ull) {
        meta->lids[r] = BIGL - (int)(blockbest & 0xffffffffull);
        meta->valid[r] = 1;
      } else {
        meta->lids[r] = -1;
        meta->valid[r] = 0;
      }
    }
    prev = blockbest;
    __syncthreads();
  }
  if (tid < 16) {
    meta->bby0[tid] = HH; meta->bby1[tid] = -1;
    meta->bbx0[tid] = WW; meta->bbx1[tid] = -1;
    meta->cls[tid] = 0;
  }
}

// ---------------- bounding boxes of selected labels ----------------
__global__ __launch_bounds__(256) void bbox_kernel(const int* __restrict__ lab,
                                                   Meta* __restrict__ meta) {
  __shared__ int lid_s[16];
  __shared__ int by0[16], by1[16], bx0[16], bx1[16];
  int tid = threadIdx.x;
  if (tid < 16) {
    lid_s[tid] = meta->lids[tid];
    by0[tid] = HH; by1[tid] = -1; bx0[tid] = WW; bx1[tid] = -1;
  }
  __syncthreads();
  int t = blockIdx.x * 256 + tid;
  int p = t * 8;
  int y = p >> 11, xbase = p & 2047;
  int4 a = *(const int4*)(lab + p), b = *(const int4*)(lab + p + 4);
  int v[8] = {a.x, a.y, a.z, a.w, b.x, b.y, b.z, b.w};
  int prev = BIGL, kprev = -1, xs = 0, xe = 0;
#pragma unroll
  for (int j = 0; j < 8; ++j) {
    int l = v[j];
    if (l == prev) { xe = xbase + j; continue; }
    if (kprev >= 0) {
      atomicMin(&by0[kprev], y); atomicMax(&by1[kprev], y);
      atomicMin(&bx0[kprev], xs); atomicMax(&bx1[kprev], xe);
    }
    prev = l; xs = xe = xbase + j; kprev = -1;
    if (l != BIGL) {
      for (int k = 0; k < 16; ++k)
        if (lid_s[k] == l) { kprev = k; break; }
    }
  }
  if (kprev >= 0) {
    atomicMin(&by0[kprev], y); atomicMax(&by1[kprev], y);
    atomicMin(&bx0[kprev], xs); atomicMax(&bx1[kprev], xe);
  }
  __syncthreads();
  if (tid < 16 && by1[tid] >= 0) {
    atomicMin(&meta->bby0[tid], by0[tid]); atomicMax(&meta->bby1[tid], by1[tid]);
    atomicMin(&meta->bbx0[tid], bx0[tid]); atomicMax(&meta->bbx1[tid], bx1[tid]);
  }
}

// ---------------- classifier conv1 with fused ROI bilinear (7-row LDS staging) --
__global__ __launch_bounds__(256) void cconv1_kernel(const float* __restrict__ img,
                                                     const float* __restrict__ cw1,
                                                     const Meta* __restrict__ meta,
                                                     float* __restrict__ h1c) {
  int k = blockIdx.y, oy = blockIdx.x;
  if (!meta->valid[k]) return;
  __shared__ float srow[7][CSZ];
  float y0 = (float)meta->bby0[k], y1 = (float)meta->bby1[k];
  float x0 = (float)meta->bbx0[k], x1 = (float)meta->bbx1[k];
  for (int idx = threadIdx.x; idx < 7 * CSZ; idx += 256) {
    int rr = idx / CSZ, j = idx - rr * CSZ;
    int i = oy * 4 + rr;
    float ti = (float)i / 226.f, tj = (float)j / 226.f;
    float gy = y0 + ti * (y1 - y0);
    float gx = x0 + tj * (x1 - x0);
    int yf = (int)floorf(gy); yf = yf < 0 ? 0 : (yf > HH - 2 ? HH - 2 : yf);
    int xf = (int)floorf(gx); xf = xf < 0 ? 0 : (xf > WW - 2 ? WW - 2 : xf);
    float fy = gy - (float)yf, fx = gx - (float)xf;
    const float* r0 = img + yf * WW + xf;
    float v00 = r0[0], v01 = r0[1], v10 = r0[WW], v11 = r0[WW + 1];
    srow[rr][j] = (1.f - fy) * ((1.f - fx) * v00 + fx * v01) +
                  fy * ((1.f - fx) * v10 + fx * v11);
  }
  __syncthreads();
  for (int idx = threadIdx.x; idx < 16 * 56; idx += 256) {
    int ch = idx / 56, ox = idx - ch * 56;
    const float* wp = cw1 + ch * 49;
    float s = 0.f;
#pragma unroll
    for (int dy = 0; dy < 7; ++dy)
#pragma unroll
      for (int dx = 0; dx < 7; ++dx)
        s += srow[dy][ox * 4 + dx] * wp[dy * 7 + dx];
    h1c[((k * 16 + ch) * 56 + oy) * 56 + ox] = s > 0.f ? s : 0.f;
  }
}

// ---------------- classifier conv2: 16->32, 3x3, stride 2, VALID ----------------
__global__ __launch_bounds__(256) void cconv2_kernel(const float* __restrict__ h1c,
                                                     const float* __restrict__ cw2,
                                                     const Meta* __restrict__ meta,
                                                     float* __restrict__ h2c) {
  int k = blockIdx.y, oy = blockIdx.x;
  if (!meta->valid[k]) return;
  for (int idx = threadIdx.x; idx < 32 * 27; idx += 256) {
    int ch = idx / 27, ox = idx - ch * 27;
    float s = 0.f;
    for (int ci = 0; ci < 16; ++ci) {
      const float* hp = h1c + ((k * 16 + ci) * 56 + oy * 2) * 56 + ox * 2;
      const float* wp = cw2 + (ch * 16 + ci) * 9;
#pragma unroll
      for (int dy = 0; dy < 3; ++dy)
#pragma unroll
        for (int dx = 0; dx < 3; ++dx) s += hp[dy * 56 + dx] * wp[dy * 3 + dx];
    }
    h2c[((k * 32 + ch) * 27 + oy) * 27 + ox] = s > 0.f ? s : 0.f;
  }
}

// ---------------- global mean pool + fc + argmax ----------------
__global__ __launch_bounds__(256) void poolfc_kernel(const float* __restrict__ h2c,
                                                     const float* __restrict__ fc,
                                                     Meta* __restrict__ meta) {
  int k = blockIdx.x;
  if (!meta->valid[k]) return;
  __shared__ float sums[8][32];
  int tid = threadIdx.x;
  int c = tid & 31, part = tid >> 5;
  float s = 0.f;
  const float* hp = h2c + (k * 32 + c) * 729;
  for (int j = part; j < 729; j += 8) s += hp[j];
  sums[part][c] = s;
  __syncthreads();
  if (tid < 32) {
    float g = 0.f;
#pragma unroll
    for (int p2 = 0; p2 < 8; ++p2) g += sums[p2][tid];
    sums[0][tid] = g / 729.f;
  }
  __syncthreads();
  if (tid == 0) {
    float best = -1e30f;
    int bi = 0;
    for (int j = 0; j < NCLS; ++j) {
      float lg = 0.f;
      for (int c2 = 0; c2 < 32; ++c2) lg += sums[0][c2] * fc[c2 * NCLS + j];
      if (lg > best) { best = lg; bi = j; }
    }
    meta->cls[k] = bi;
  }
}

// ---------------- final: write 4-channel one-hot masks ----------------
__global__ __launch_bounds__(256) void final_kernel(const float* labf,
                                                    const Meta* __restrict__ meta,
                                                    float* out) {
  __shared__ int lid_s[16];
  __shared__ int cls_s[16];
  int tid = threadIdx.x;
  if (tid < 16) {
    lid_s[tid] = meta->valid[tid] ? meta->lids[tid] : -1;
    cls_s[tid] = meta->cls[tid];
  }
  __syncthreads();
  int t = blockIdx.x * 256 + tid;
  int p = t * 4;
  float4 lf = *(const float4*)(labf + p);
  int l4[4] = {__float_as_int(lf.x), __float_as_int(lf.y), __float_as_int(lf.z),
               __float_as_int(lf.w)};
  int cj[4];
#pragma unroll
  for (int j = 0; j < 4; ++j) {
    cj[j] = -1;
    int l = l4[j];
    if (l != BIGL) {
      for (int k = 0; k < 16; ++k)
        if (lid_s[k] == l) { cj[j] = cls_s[k]; break; }
    }
  }
#pragma unroll
  for (int c = 0; c < 4; ++c) {
    float4 w4 = make_float4(cj[0] == c ? 1.f : 0.f, cj[1] == c ? 1.f : 0.f,
                            cj[2] == c ? 1.f : 0.f, cj[3] == c ? 1.f : 0.f);
    *(float4*)(out + (size_t)c * HWTOT + p) = w4;
  }
}

extern "C" void kernel_launch(void* const* d_in, const int* in_sizes, int n_in,
                              void* d_out, int out_size, void* d_ws, size_t ws_size,
                              hipStream_t stream) {
  const float* x = (const float*)d_in[0];
  const float* w1 = (const float*)d_in[1];
  const float* w2 = (const float*)d_in[2];
  const float* w3 = (const float*)d_in[3];
  const float* cw1 = (const float*)d_in[4];
  const float* cw2 = (const float*)d_in[5];
  const float* fc = (const float*)d_in[6];

  char* base = (char*)d_out;
  int* lab_a = (int*)(base + OFF_LABA);
  int* lab_b = (int*)(base + OFF_LABB);
  float* h1c = (float*)(base + OFF_H1C);
  float* h2c = (float*)(base + OFF_H2C);
  int2* cand = (int2*)(base + OFF_CAND);
  u64* cand16 = (u64*)(base + OFF_CAND16);
  int* counts = (int*)(base + OFF_COUNTS);
  ushort* wfrag = (ushort*)(base + OFF_W2R);
  float* w1p = (float*)(base + OFF_W1P);
  int* list = (int*)(base + OFF_LIST);
  int* cand_count = (int*)d_ws;
  int* list_count = (int*)((char*)d_ws + 64);
  Meta* meta = (Meta*)((char*)d_ws + 256);

  hipMemsetAsync(counts, 0, (size_t)(HWTOT + 1) * sizeof(int), stream);

  prep_kernel<<<72, 256, 0, stream>>>(w2, w1, wfrag, w1p, (int*)d_ws);
  cascade_kernel<<<dim3(64, 128), 512, 0, stream>>>(x, w1p, wfrag, w3, lab_a, list,
                                                    list_count);
  recheck_kernel<<<2048, 256, 0, stream>>>(x, w1, w2, w3, list, list_count, lab_a);

  // 64 exact CC steps = 4 launches x 16 register-resident steps
  for (int l = 0; l < 4; ++l) {
    const int* src = (l & 1) ? lab_b : lab_a;
    int* dst = (l & 1) ? lab_a : lab_b;
    cc16_kernel<<<1024, 256, 0, stream>>>(src, dst);
  }
  // even # of launches -> final labels in lab_a

  hist_kernel<<<2048, 256, 0, stream>>>(lab_a, counts);
  cand_kernel<<<16384, 256, 0, stream>>>(counts, cand, cand_count);
  top16a_kernel<<<32, 256, 0, stream>>>(cand, cand_count, cand16);
  top16b_kernel<<<1, 256, 0, stream>>>(cand16, meta);
  bbox_kernel<<<2048, 256, 0, stream>>>(lab_a, meta);
  cconv1_kernel<<<dim3(56, 16), 256, 0, stream>>>(x, cw1, meta, h1c);
  cconv2_kernel<<<dim3(27, 16), 256, 0, stream>>>(h1c, cw2, meta, h2c);
  poolfc_kernel<<<16, 256, 0, stream>>>(h2c, fc, meta);
  final_kernel<<<4096, 256, 0, stream>>>((const float*)d_out, meta, (float*)d_out);
}